// Round 4
// baseline (4227.934 us; speedup 1.0000x reference)
//
#include <hip/hip_runtime.h>
#include <math.h>

// FCLTCQNetwork: liquid-time-constant cell scan + MLP head.
// B=4096 T=128 D=64 U=64 A=8 QH=64 UNFOLDS=6.
// Round 3: 8 waves/block (2 waves/SIMD) x E=2 elements/wave so the trans pipe
// (exp2/rcp, 16cy/wave64 op) of one wave overlaps the VALU/LDS of the other.
// Paired reciprocal: R = rcp(dA*dB); 1/dA = dB*R, 1/dB = dA*R  -> 1.5 trans
// ops per sigmoid instead of 2. z clamped to <=60 so dA*dB can't overflow.
//   sigmoid(sigma*(x-mu)) = rcp(1 + exp2(k*x + c)), k=-log2e*sigma, c=log2e*sigma*mu
// Params packed float4 (k, c, w_signed, |w|) in LDS, one ds_read_b128/term.

namespace {

constexpr int kB = 4096, kT = 128, kD = 64, kU = 64, kA = 8, kQH = 64, kUnf = 6;
constexpr float kEps = 1e-8f;
constexpr float kLog2e = 1.4426950408889634f;
constexpr float kZClamp = 60.0f;
constexpr int kWaves = 8;             // waves per block (2 per SIMD)
constexpr int kEPW = 2;               // batch elements per wave
constexpr int kBlock = kWaves * 64;   // 512 threads
constexpr int kBPB = kWaves * kEPW;   // 16 batch elements per block

#if __has_builtin(__builtin_amdgcn_exp2f)
#define EXP2F(x) __builtin_amdgcn_exp2f(x)
#else
#define EXP2F(x) exp2f(x)
#endif

__device__ __forceinline__ float rcp_fast(float x) {
  return __builtin_amdgcn_rcpf(x);
}

__device__ __forceinline__ float bcast(float x, int l) {
  return __int_as_float(__builtin_amdgcn_readlane(__float_as_int(x), l));
}

__device__ __forceinline__ float softplus(float x) { return log1pf(expf(x)); }

__global__ __launch_bounds__(kBlock, 2)
void ltc_fused(const float* __restrict__ obs, const float* __restrict__ input_w,
               const float* __restrict__ input_b, const float* __restrict__ s_mu,
               const float* __restrict__ s_sigma, const float* __restrict__ s_w,
               const float* __restrict__ s_erev, const float* __restrict__ r_mu,
               const float* __restrict__ r_sigma, const float* __restrict__ r_w,
               const float* __restrict__ r_erev, const float* __restrict__ gleak,
               const float* __restrict__ vleak, const float* __restrict__ cm,
               const float* __restrict__ W1, const float* __restrict__ b1,
               const float* __restrict__ W2, const float* __restrict__ b2,
               float* __restrict__ q_out, float* __restrict__ h_out) {
  // Packed transformed params: (k, c, w_signed, |w|). 64KB + 64KB = 128KB.
  __shared__ float4 sp[kD * kU];  // sensory, layout [d][i]
  __shared__ float4 rp[kU * kU];  // recurrent, layout [j][i]

  const int tid = threadIdx.x;
  for (int idx = tid; idx < kD * kU; idx += kBlock) {
    const float sg = s_sigma[idx];
    const float swa = softplus(s_w[idx]);
    sp[idx] = make_float4(-kLog2e * sg, kLog2e * sg * s_mu[idx],
                          swa * s_erev[idx], swa);
    const float rg = r_sigma[idx];
    const float rwa = softplus(r_w[idx]);
    rp[idx] = make_float4(-kLog2e * rg, kLog2e * rg * r_mu[idx],
                          rwa * r_erev[idx], rwa);
  }
  __syncthreads();

  const int lane = tid & 63;
  const int wid = tid >> 6;
  const int b0 = (blockIdx.x * kWaves + wid) * kEPW;  // this wave's 2 elements

  // Per-neuron (lane = i) scalars.
  const float gl   = softplus(gleak[lane]);
  const float glvl = gl * vleak[lane];
  const float cmt  = softplus(cm[lane]) * (float)kUnf;
  const float iw   = input_w[lane];
  const float ib   = input_b[lane];

  const float* ob[kEPW];
#pragma unroll
  for (int e = 0; e < kEPW; ++e) ob[e] = obs + (size_t)(b0 + e) * kT * kD;

  float v[kEPW], o[kEPW];
#pragma unroll
  for (int e = 0; e < kEPW; ++e) {
    v[e] = 0.0f;
    o[e] = ob[e][lane];  // prefetch t=0
  }

#pragma unroll 1
  for (int t = 0; t < kT; ++t) {
    // prefetch next timestep's obs; latency hides behind this iteration
    const int tn = (t + 1 < kT) ? (t + 1) : t;
    float nx[kEPW];
#pragma unroll
    for (int e = 0; e < kEPW; ++e) nx[e] = ob[e][tn * kD + lane];

    float xi[kEPW];
#pragma unroll
    for (int e = 0; e < kEPW; ++e) xi[e] = fmaf(o[e], iw, ib);

    // Sensory synapse sums (depend only on x; once per timestep).
    float ns[kEPW], ds[kEPW];
#pragma unroll
    for (int e = 0; e < kEPW; ++e) { ns[e] = 0.0f; ds[e] = 0.0f; }
#pragma unroll 8
    for (int d = 0; d < kD; d += 2) {
      const float4 pA = sp[d * kU + lane];
      const float4 pB = sp[(d + 1) * kU + lane];
#pragma unroll
      for (int e = 0; e < kEPW; ++e) {
        const float xA = bcast(xi[e], d);
        const float xB = bcast(xi[e], d + 1);
        const float zA = fminf(fmaf(pA.x, xA, pA.y), kZClamp);
        const float zB = fminf(fmaf(pB.x, xB, pB.y), kZClamp);
        const float dA = 1.0f + EXP2F(zA);
        const float dB = 1.0f + EXP2F(zB);
        const float R = rcp_fast(dA * dB);
        const float gA = dB * R;
        const float gB = dA * R;
        ns[e] = fmaf(gA, pA.z, ns[e]);
        ds[e] = fmaf(gA, pA.w, ds[e]);
        ns[e] = fmaf(gB, pB.z, ns[e]);
        ds[e] = fmaf(gB, pB.w, ds[e]);
      }
    }

    // ODE unfolds.
#pragma unroll 1
    for (int u = 0; u < kUnf; ++u) {
      float num[kEPW], den[kEPW];
#pragma unroll
      for (int e = 0; e < kEPW; ++e) { num[e] = 0.0f; den[e] = 0.0f; }
#pragma unroll 8
      for (int j = 0; j < kU; j += 2) {
        const float4 pA = rp[j * kU + lane];
        const float4 pB = rp[(j + 1) * kU + lane];
#pragma unroll
        for (int e = 0; e < kEPW; ++e) {
          const float vA = bcast(v[e], j);
          const float vB = bcast(v[e], j + 1);
          const float zA = fminf(fmaf(pA.x, vA, pA.y), kZClamp);
          const float zB = fminf(fmaf(pB.x, vB, pB.y), kZClamp);
          const float dA = 1.0f + EXP2F(zA);
          const float dB = 1.0f + EXP2F(zB);
          const float R = rcp_fast(dA * dB);
          const float gA = dB * R;
          const float gB = dA * R;
          num[e] = fmaf(gA, pA.z, num[e]);
          den[e] = fmaf(gA, pA.w, den[e]);
          num[e] = fmaf(gB, pB.z, num[e]);
          den[e] = fmaf(gB, pB.w, den[e]);
        }
      }
#pragma unroll
      for (int e = 0; e < kEPW; ++e) {
        const float nt = fmaf(cmt, v[e], glvl) + num[e] + ns[e];
        const float dt = cmt + gl + den[e] + ds[e] + kEps;
        v[e] = nt * rcp_fast(dt);
      }
    }

#pragma unroll
    for (int e = 0; e < kEPW; ++e) o[e] = nx[e];
  }

  // hidden output
#pragma unroll
  for (int e = 0; e < kEPW; ++e) h_out[(size_t)(b0 + e) * kU + lane] = v[e];

  // Head: h1 = relu(v @ W1 + b1); q = h1 @ W2 + b2. Once per batch, cheap.
  float h1[kEPW];
#pragma unroll
  for (int e = 0; e < kEPW; ++e) h1[e] = b1[lane];
#pragma unroll 16
  for (int j = 0; j < kU; ++j) {
    const float w1 = W1[j * kQH + lane];
#pragma unroll
    for (int e = 0; e < kEPW; ++e) h1[e] = fmaf(bcast(v[e], j), w1, h1[e]);
  }
#pragma unroll
  for (int e = 0; e < kEPW; ++e) h1[e] = fmaxf(h1[e], 0.0f);

  float qa[kEPW][kA];
#pragma unroll
  for (int a = 0; a < kA; ++a) {
    const float w2 = W2[lane * kA + a];
#pragma unroll
    for (int e = 0; e < kEPW; ++e) qa[e][a] = h1[e] * w2;
  }
#pragma unroll
  for (int s = 32; s > 0; s >>= 1) {
#pragma unroll
    for (int a = 0; a < kA; ++a) {
#pragma unroll
      for (int e = 0; e < kEPW; ++e) qa[e][a] += __shfl_xor(qa[e][a], s, 64);
    }
  }
  if (lane == 0) {
#pragma unroll
    for (int a = 0; a < kA; ++a) {
#pragma unroll
      for (int e = 0; e < kEPW; ++e) {
        q_out[(size_t)(b0 + e) * kA + a] = qa[e][a] + b2[a];
      }
    }
  }
}

}  // namespace

extern "C" void kernel_launch(void* const* d_in, const int* in_sizes, int n_in,
                              void* d_out, int out_size, void* d_ws, size_t ws_size,
                              hipStream_t stream) {
  const float* obs     = (const float*)d_in[0];
  const float* input_w = (const float*)d_in[1];
  const float* input_b = (const float*)d_in[2];
  const float* s_mu    = (const float*)d_in[3];
  const float* s_sigma = (const float*)d_in[4];
  const float* s_w     = (const float*)d_in[5];
  const float* s_erev  = (const float*)d_in[6];
  const float* r_mu    = (const float*)d_in[7];
  const float* r_sigma = (const float*)d_in[8];
  const float* r_w     = (const float*)d_in[9];
  const float* r_erev  = (const float*)d_in[10];
  const float* gleak   = (const float*)d_in[11];
  const float* vleak   = (const float*)d_in[12];
  const float* cm      = (const float*)d_in[13];
  const float* W1      = (const float*)d_in[14];
  const float* b1      = (const float*)d_in[15];
  const float* W2      = (const float*)d_in[16];
  const float* b2      = (const float*)d_in[17];

  float* q_out = (float*)d_out;
  float* h_out = q_out + (size_t)kB * kA;

  hipLaunchKernelGGL(ltc_fused, dim3(kB / kBPB), dim3(kBlock), 0, stream,
                     obs, input_w, input_b, s_mu, s_sigma, s_w, s_erev,
                     r_mu, r_sigma, r_w, r_erev, gleak, vleak, cm,
                     W1, b1, W2, b2, q_out, h_out);
}

// Round 5
// 3986.747 us; speedup vs baseline: 1.0605x; 1.0605x over previous
//
#include <hip/hip_runtime.h>
#include <math.h>

// FCLTCQNetwork: liquid-time-constant cell scan + MLP head.
// B=4096 T=128 D=64 U=64 A=8 QH=64 UNFOLDS=6.
// Round 4: round-2 structure (4 waves/block, E=4 elements/wave, 1 wave/SIMD,
// 256 blocks) + reciprocal sharing across ELEMENT PAIRS of the same j:
//   R = rcp(d0*d1); g0 = d1*R; g1 = d0*R   (one rcp serves two sigmoids)
// No clamp needed for the recurrent part: |v| <= 1 inductively (|ns|<=ds,
// |vleak|<=0.2) so |z| <= 1.44*8*1.8 ~ 21 -> pair product <= 2^42.
// Sensory part kept exact round-2 form (x unbounded; per-term rcp, inf->0).
//   sigmoid(sigma*(x-mu)) = rcp(1 + exp2(k*x + c)), k=-log2e*sigma, c=log2e*sigma*mu
// Params packed float4 (k, c, w_signed, |w|) in LDS, one ds_read_b128/term.

namespace {

constexpr int kB = 4096, kT = 128, kD = 64, kU = 64, kA = 8, kQH = 64, kUnf = 6;
constexpr float kEps = 1e-8f;
constexpr float kLog2e = 1.4426950408889634f;
constexpr int kWaves = 4;             // waves per block (1 per SIMD)
constexpr int kEPW = 4;               // batch elements per wave
constexpr int kBlock = kWaves * 64;   // 256 threads
constexpr int kBPB = kWaves * kEPW;   // 16 batch elements per block

#if __has_builtin(__builtin_amdgcn_exp2f)
#define EXP2F(x) __builtin_amdgcn_exp2f(x)
#else
#define EXP2F(x) exp2f(x)
#endif

__device__ __forceinline__ float rcp_fast(float x) {
  return __builtin_amdgcn_rcpf(x);
}

__device__ __forceinline__ float bcast(float x, int l) {
  return __int_as_float(__builtin_amdgcn_readlane(__float_as_int(x), l));
}

__device__ __forceinline__ float softplus(float x) { return log1pf(expf(x)); }

__global__ __launch_bounds__(kBlock, 1)
void ltc_fused(const float* __restrict__ obs, const float* __restrict__ input_w,
               const float* __restrict__ input_b, const float* __restrict__ s_mu,
               const float* __restrict__ s_sigma, const float* __restrict__ s_w,
               const float* __restrict__ s_erev, const float* __restrict__ r_mu,
               const float* __restrict__ r_sigma, const float* __restrict__ r_w,
               const float* __restrict__ r_erev, const float* __restrict__ gleak,
               const float* __restrict__ vleak, const float* __restrict__ cm,
               const float* __restrict__ W1, const float* __restrict__ b1,
               const float* __restrict__ W2, const float* __restrict__ b2,
               float* __restrict__ q_out, float* __restrict__ h_out) {
  // Packed transformed params: (k, c, w_signed, |w|). 64KB + 64KB = 128KB.
  __shared__ float4 sp[kD * kU];  // sensory, layout [d][i]
  __shared__ float4 rp[kU * kU];  // recurrent, layout [j][i]

  const int tid = threadIdx.x;
  for (int idx = tid; idx < kD * kU; idx += kBlock) {
    const float sg = s_sigma[idx];
    const float swa = softplus(s_w[idx]);
    sp[idx] = make_float4(-kLog2e * sg, kLog2e * sg * s_mu[idx],
                          swa * s_erev[idx], swa);
    const float rg = r_sigma[idx];
    const float rwa = softplus(r_w[idx]);
    rp[idx] = make_float4(-kLog2e * rg, kLog2e * rg * r_mu[idx],
                          rwa * r_erev[idx], rwa);
  }
  __syncthreads();

  const int lane = tid & 63;
  const int wid = tid >> 6;
  const int b0 = (blockIdx.x * kWaves + wid) * kEPW;  // this wave's 4 elements

  // Per-neuron (lane = i) scalars.
  const float gl   = softplus(gleak[lane]);
  const float glvl = gl * vleak[lane];
  const float cmt  = softplus(cm[lane]) * (float)kUnf;
  const float iw   = input_w[lane];
  const float ib   = input_b[lane];

  const float* ob[kEPW];
#pragma unroll
  for (int e = 0; e < kEPW; ++e) ob[e] = obs + (size_t)(b0 + e) * kT * kD;

  float v[kEPW], o[kEPW];
#pragma unroll
  for (int e = 0; e < kEPW; ++e) {
    v[e] = 0.0f;
    o[e] = ob[e][lane];  // prefetch t=0
  }

#pragma unroll 1
  for (int t = 0; t < kT; ++t) {
    // prefetch next timestep's obs; latency hides behind this iteration
    const int tn = (t + 1 < kT) ? (t + 1) : t;
    float nx[kEPW];
#pragma unroll
    for (int e = 0; e < kEPW; ++e) nx[e] = ob[e][tn * kD + lane];

    float xi[kEPW];
#pragma unroll
    for (int e = 0; e < kEPW; ++e) xi[e] = fmaf(o[e], iw, ib);

    // Sensory synapse sums (x unbounded -> per-term rcp, overflow-safe).
    float ns[kEPW], ds[kEPW];
#pragma unroll
    for (int e = 0; e < kEPW; ++e) { ns[e] = 0.0f; ds[e] = 0.0f; }
#pragma unroll 16
    for (int d = 0; d < kD; ++d) {
      const float4 p = sp[d * kU + lane];
#pragma unroll
      for (int e = 0; e < kEPW; ++e) {
        const float xd = bcast(xi[e], d);
        const float ex = EXP2F(fmaf(p.x, xd, p.y));
        const float g = rcp_fast(1.0f + ex);
        ns[e] = fmaf(g, p.z, ns[e]);
        ds[e] = fmaf(g, p.w, ds[e]);
      }
    }

    // ODE unfolds. |v| <= 1 -> |z| <= ~21 -> pair products can't overflow.
#pragma unroll 1
    for (int u = 0; u < kUnf; ++u) {
      float num[kEPW], den[kEPW];
#pragma unroll
      for (int e = 0; e < kEPW; ++e) { num[e] = 0.0f; den[e] = 0.0f; }
#pragma unroll 8
      for (int j = 0; j < kU; ++j) {
        const float4 p = rp[j * kU + lane];
        float dd[kEPW];
#pragma unroll
        for (int e = 0; e < kEPW; ++e) {
          const float vj = bcast(v[e], j);
          dd[e] = 1.0f + EXP2F(fmaf(p.x, vj, p.y));
        }
#pragma unroll
        for (int e = 0; e < kEPW; e += 2) {
          const float R = rcp_fast(dd[e] * dd[e + 1]);
          const float g0 = dd[e + 1] * R;
          const float g1 = dd[e] * R;
          num[e]     = fmaf(g0, p.z, num[e]);
          den[e]     = fmaf(g0, p.w, den[e]);
          num[e + 1] = fmaf(g1, p.z, num[e + 1]);
          den[e + 1] = fmaf(g1, p.w, den[e + 1]);
        }
      }
#pragma unroll
      for (int e = 0; e < kEPW; ++e) {
        const float nt = fmaf(cmt, v[e], glvl) + num[e] + ns[e];
        const float dt = cmt + gl + den[e] + ds[e] + kEps;
        v[e] = nt * rcp_fast(dt);
      }
    }

#pragma unroll
    for (int e = 0; e < kEPW; ++e) o[e] = nx[e];
  }

  // hidden output
#pragma unroll
  for (int e = 0; e < kEPW; ++e) h_out[(size_t)(b0 + e) * kU + lane] = v[e];

  // Head: h1 = relu(v @ W1 + b1); q = h1 @ W2 + b2. Once per batch, cheap.
  float h1[kEPW];
#pragma unroll
  for (int e = 0; e < kEPW; ++e) h1[e] = b1[lane];
#pragma unroll 16
  for (int j = 0; j < kU; ++j) {
    const float w1 = W1[j * kQH + lane];
#pragma unroll
    for (int e = 0; e < kEPW; ++e) h1[e] = fmaf(bcast(v[e], j), w1, h1[e]);
  }
#pragma unroll
  for (int e = 0; e < kEPW; ++e) h1[e] = fmaxf(h1[e], 0.0f);

  float qa[kEPW][kA];
#pragma unroll
  for (int a = 0; a < kA; ++a) {
    const float w2 = W2[lane * kA + a];
#pragma unroll
    for (int e = 0; e < kEPW; ++e) qa[e][a] = h1[e] * w2;
  }
#pragma unroll
  for (int s = 32; s > 0; s >>= 1) {
#pragma unroll
    for (int a = 0; a < kA; ++a) {
#pragma unroll
      for (int e = 0; e < kEPW; ++e) qa[e][a] += __shfl_xor(qa[e][a], s, 64);
    }
  }
  if (lane == 0) {
#pragma unroll
    for (int a = 0; a < kA; ++a) {
#pragma unroll
      for (int e = 0; e < kEPW; ++e) {
        q_out[(size_t)(b0 + e) * kA + a] = qa[e][a] + b2[a];
      }
    }
  }
}

}  // namespace

extern "C" void kernel_launch(void* const* d_in, const int* in_sizes, int n_in,
                              void* d_out, int out_size, void* d_ws, size_t ws_size,
                              hipStream_t stream) {
  const float* obs     = (const float*)d_in[0];
  const float* input_w = (const float*)d_in[1];
  const float* input_b = (const float*)d_in[2];
  const float* s_mu    = (const float*)d_in[3];
  const float* s_sigma = (const float*)d_in[4];
  const float* s_w     = (const float*)d_in[5];
  const float* s_erev  = (const float*)d_in[6];
  const float* r_mu    = (const float*)d_in[7];
  const float* r_sigma = (const float*)d_in[8];
  const float* r_w     = (const float*)d_in[9];
  const float* r_erev  = (const float*)d_in[10];
  const float* gleak   = (const float*)d_in[11];
  const float* vleak   = (const float*)d_in[12];
  const float* cm      = (const float*)d_in[13];
  const float* W1      = (const float*)d_in[14];
  const float* b1      = (const float*)d_in[15];
  const float* W2      = (const float*)d_in[16];
  const float* b2      = (const float*)d_in[17];

  float* q_out = (float*)d_out;
  float* h_out = q_out + (size_t)kB * kA;

  hipLaunchKernelGGL(ltc_fused, dim3(kB / kBPB), dim3(kBlock), 0, stream,
                     obs, input_w, input_b, s_mu, s_sigma, s_w, s_erev,
                     r_mu, r_sigma, r_w, r_erev, gleak, vleak, cm,
                     W1, b1, W2, b2, q_out, h_out);
}